// Round 1
// baseline (590.408 us; speedup 1.0000x reference)
//
#include <hip/hip_runtime.h>
#include <math.h>

// Problem constants (fixed-shape problem)
#define NN 131072   // nodes
#define G  256      // groups
#define E  384      // embed
#define H  6        // heads
#define DH 64       // head dim
#define OUTD 256    // output dim
#define MAXN 1024   // max segment length

// Workspace layout (float indices)
#define WS_QK   0                       // 6*384 folded q@Wk
#define WS_C    2304                    // 6 folded q@bk
#define WS_OFF  2432                    // 256 int32 segment offsets
#define WS_SC   4096                    // N*6 scores
#define WS_XBAR (4096 + NN*6)           // 256*6*384 attn-weighted feature means

// ---------------------------------------------------------------------------
// K0: segment offsets (scan) + fold query through Wq and Wk.
// qk[h][e] = sum_d qv[h*64+d]*Wk[h*64+d][e],  c[h] = sum_d qv[h*64+d]*bk[h*64+d]
// qv = 0.125*(query@Wq.T + bq)   (1/sqrt(64) pre-scale, as PyTorch MHA)
// ---------------------------------------------------------------------------
__global__ __launch_bounds__(384) void k0_prep(
    const int* __restrict__ sizes, const float* __restrict__ query,
    const float* __restrict__ Wq, const float* __restrict__ bq,
    const float* __restrict__ Wk, const float* __restrict__ bk,
    float* __restrict__ wsf) {
  __shared__ int s_scan[G];
  __shared__ float s_q[E];
  __shared__ float s_qv[E];
  const int tid = threadIdx.x;
  const int lane = tid & 63;
  const int wv = tid >> 6;            // 0..5

  if (tid < G) s_scan[tid] = sizes[tid];
  if (tid < E) s_q[tid] = query[tid];
  __syncthreads();
  // Hillis-Steele inclusive scan over 256 sizes
  for (int d = 1; d < G; d <<= 1) {
    int t = 0;
    if (tid < G && tid >= d) t = s_scan[tid - d];
    __syncthreads();
    if (tid < G) s_scan[tid] += t;
    __syncthreads();
  }
  int* offs = (int*)(wsf + WS_OFF);
  if (tid < G) offs[tid] = s_scan[tid] - sizes[tid];   // exclusive

  // q_vec: wave-per-row (coalesced reads of Wq rows)
  for (int i = wv; i < E; i += 6) {
    const float* wrow = Wq + (size_t)i * E;
    float a = 0.f;
#pragma unroll
    for (int j = 0; j < 6; j++) a += wrow[j * 64 + lane] * s_q[j * 64 + lane];
#pragma unroll
    for (int mm = 1; mm < 64; mm <<= 1) a += __shfl_xor(a, mm, 64);
    if (lane == 0) s_qv[i] = 0.125f * (a + bq[i]);
  }
  __syncthreads();

  // qk: thread t owns column e=t for all 6 heads; loads coalesced across threads
#pragma unroll
  for (int h = 0; h < H; h++) {
    const float* wk = Wk + (size_t)(h * DH) * E + tid;
    float a = 0.f;
#pragma unroll 8
    for (int d = 0; d < DH; d++) a += s_qv[h * DH + d] * wk[(size_t)d * E];
    wsf[WS_QK + h * E + tid] = a;
  }
  if (tid < H) {
    float a = 0.f;
    for (int d = 0; d < DH; d++) a += s_qv[tid * DH + d] * bk[tid * DH + d];
    wsf[WS_C + tid] = a;
  }
}

// ---------------------------------------------------------------------------
// K1: scores[n][h] = x[n]·qk[h] + c[h].  Wave-per-node, qk in registers,
// butterfly reduce. Perfectly balanced flat pass over node_feat (201 MB).
// ---------------------------------------------------------------------------
__global__ __launch_bounds__(256) void k1_scores(
    const float* __restrict__ x, const float* __restrict__ wsf,
    float* __restrict__ scores) {
  const int lane = threadIdx.x & 63;
  const int wid = (blockIdx.x * blockDim.x + threadIdx.x) >> 6;
  const int nwaves = (gridDim.x * blockDim.x) >> 6;

  float qkr[H][6], cr[H];
#pragma unroll
  for (int h = 0; h < H; h++) {
    cr[h] = wsf[WS_C + h];
#pragma unroll
    for (int j = 0; j < 6; j++) qkr[h][j] = wsf[WS_QK + h * E + j * 64 + lane];
  }

  for (int n = wid; n < NN; n += nwaves) {
    const float* xr = x + (size_t)n * E;
    float xv[6];
#pragma unroll
    for (int j = 0; j < 6; j++) xv[j] = xr[j * 64 + lane];
    float p[H];
#pragma unroll
    for (int h = 0; h < H; h++) {
      float a = 0.f;
#pragma unroll
      for (int j = 0; j < 6; j++) a += xv[j] * qkr[h][j];
      p[h] = a;
    }
#pragma unroll
    for (int h = 0; h < H; h++)
#pragma unroll
      for (int mm = 1; mm < 64; mm <<= 1) p[h] += __shfl_xor(p[h], mm, 64);
    if (lane < H) {
      float v = p[0] + cr[0];
#pragma unroll
      for (int h = 1; h < H; h++) v = (lane == h) ? (p[h] + cr[h]) : v;
      scores[(size_t)n * H + lane] = v;
    }
  }
}

// ---------------------------------------------------------------------------
// K2: per (group, e-chunk of 128): softmax over segment (in LDS) then
// xbar[g][h][e] = sum_n attn[n][h] * x[off+n][e].  768 blocks x 128 threads.
// g = blk/3 so consecutive blocks (-> different CUs) get different chunks,
// and a CU's 3 blocks land on ~independent groups (load balance).
// ---------------------------------------------------------------------------
__global__ __launch_bounds__(128) void k2_pool(
    const float* __restrict__ x, const int* __restrict__ sizes,
    const float* __restrict__ wsf, float* __restrict__ xbar) {
  __shared__ float pbuf[H][MAXN];      // 24 KB attn weights (unnormalized)
  __shared__ float redm[2][H];
  __shared__ float redl[2][H];
  const int tid = threadIdx.x;
  const int wv = tid >> 6;
  const int c = blockIdx.x % 3;        // e-chunk
  const int g = blockIdx.x / 3;
  const int* offs = (const int*)(wsf + WS_OFF);
  const int off = offs[g];
  const int Ng = sizes[g];
  const float* sc = wsf + WS_SC + (size_t)off * H;

  // Phase A: stage scores into LDS, per-head running max
  float m[H];
#pragma unroll
  for (int h = 0; h < H; h++) m[h] = -3.0e38f;
  for (int n = tid; n < Ng; n += 128) {
#pragma unroll
    for (int h = 0; h < H; h++) {
      float s = sc[(size_t)n * H + h];
      pbuf[h][n] = s;
      m[h] = fmaxf(m[h], s);
    }
  }
#pragma unroll
  for (int h = 0; h < H; h++)
#pragma unroll
    for (int mm = 1; mm < 64; mm <<= 1) m[h] = fmaxf(m[h], __shfl_xor(m[h], mm, 64));
  if ((tid & 63) == 0)
#pragma unroll
    for (int h = 0; h < H; h++) redm[wv][h] = m[h];
  __syncthreads();
#pragma unroll
  for (int h = 0; h < H; h++) m[h] = fmaxf(redm[0][h], redm[1][h]);

  // Phase B: exp in place, per-head sum
  float l[H];
#pragma unroll
  for (int h = 0; h < H; h++) l[h] = 0.f;
  for (int n = tid; n < Ng; n += 128) {
#pragma unroll
    for (int h = 0; h < H; h++) {
      float p = __expf(pbuf[h][n] - m[h]);
      pbuf[h][n] = p;
      l[h] += p;
    }
  }
  // zero-pad to multiple of 8 for the unrolled accumulate loop
  const int NgP = (Ng + 7) & ~7;
  for (int n = Ng + tid; n < NgP; n += 128)
#pragma unroll
    for (int h = 0; h < H; h++) pbuf[h][n] = 0.f;
#pragma unroll
  for (int h = 0; h < H; h++)
#pragma unroll
    for (int mm = 1; mm < 64; mm <<= 1) l[h] += __shfl_xor(l[h], mm, 64);
  if ((tid & 63) == 0)
#pragma unroll
    for (int h = 0; h < H; h++) redl[wv][h] = l[h];
  __syncthreads();                     // also orders pbuf writes before Phase C
  float inv[H];
#pragma unroll
  for (int h = 0; h < H; h++) inv[h] = 1.f / (redl[0][h] + redl[1][h]);

  // Phase C: thread t owns feature column c*128+t; stream nodes, unroll 8.
  float acc[H];
#pragma unroll
  for (int h = 0; h < H; h++) acc[h] = 0.f;
  const float* xcol = x + (size_t)off * E + c * 128 + tid;
  for (int n = 0; n < Ng; n += 8) {
    float xv[8];
#pragma unroll
    for (int k = 0; k < 8; k++) {
      int nn = n + k;
      nn = nn < Ng ? nn : Ng - 1;      // clamped; pad attn weight is 0
      xv[k] = xcol[(size_t)nn * E];
    }
#pragma unroll
    for (int h = 0; h < H; h++) {
      const float4 p0 = *(const float4*)&pbuf[h][n];      // broadcast reads
      const float4 p1 = *(const float4*)&pbuf[h][n + 4];
      acc[h] += p0.x * xv[0] + p0.y * xv[1] + p0.z * xv[2] + p0.w * xv[3]
              + p1.x * xv[4] + p1.y * xv[5] + p1.z * xv[6] + p1.w * xv[7];
    }
  }
#pragma unroll
  for (int h = 0; h < H; h++)
    xbar[((size_t)g * H + h) * E + c * 128 + tid] = acc[h] * inv[h];
}

// ---------------------------------------------------------------------------
// K3: per 3 groups: pooled = blockdiag(Wv)·xbar + bv ; out = Wo·pooled + bo ;
// final = Wp·out + bp.  86 blocks balances L2 weight re-reads vs compute.
// ---------------------------------------------------------------------------
#define TG 3
__global__ __launch_bounds__(256) void k3_chain(
    const float* __restrict__ xbar,
    const float* __restrict__ Wv, const float* __restrict__ bv,
    const float* __restrict__ Wo, const float* __restrict__ bo,
    const float* __restrict__ Wp, const float* __restrict__ bp,
    float* __restrict__ out) {
  __shared__ float xb[TG * H * E];     // 27.6 KB
  __shared__ float pooled[TG * E];
  __shared__ float om[TG * E];
  const int tid = threadIdx.x;
  const int g0 = blockIdx.x * TG;

  for (int idx = tid; idx < TG * H * E; idx += 256) {
    int gi = idx / (H * E);
    int g = g0 + gi;
    xb[idx] = (g < G) ? xbar[(size_t)g * (H * E) + (idx % (H * E))] : 0.f;
  }
  __syncthreads();

  for (int j = tid; j < TG * E; j += 256) {
    int gi = j / E, i = j % E, h = i >> 6;
    if (g0 + gi < G) {
      const float4* w4 = (const float4*)(Wv + (size_t)i * E);
      const float4* x4 = (const float4*)(xb + (gi * H + h) * E);
      float a = 0.f;
#pragma unroll 4
      for (int e = 0; e < E / 4; e++) {
        float4 w = w4[e], v = x4[e];
        a += w.x * v.x + w.y * v.y + w.z * v.z + w.w * v.w;
      }
      pooled[j] = a + bv[i];
    }
  }
  __syncthreads();

  for (int j = tid; j < TG * E; j += 256) {
    int gi = j / E, i = j % E;
    if (g0 + gi < G) {
      const float4* w4 = (const float4*)(Wo + (size_t)i * E);
      const float4* x4 = (const float4*)(pooled + gi * E);
      float a = 0.f;
#pragma unroll 4
      for (int e = 0; e < E / 4; e++) {
        float4 w = w4[e], v = x4[e];
        a += w.x * v.x + w.y * v.y + w.z * v.z + w.w * v.w;
      }
      om[j] = a + bo[i];
    }
  }
  __syncthreads();

  for (int j = tid; j < TG * OUTD; j += 256) {
    int gi = j / OUTD, o = j % OUTD;
    int g = g0 + gi;
    if (g < G) {
      const float4* w4 = (const float4*)(Wp + (size_t)o * E);
      const float4* x4 = (const float4*)(om + gi * E);
      float a = 0.f;
#pragma unroll 4
      for (int e = 0; e < E / 4; e++) {
        float4 w = w4[e], v = x4[e];
        a += w.x * v.x + w.y * v.y + w.z * v.z + w.w * v.w;
      }
      out[(size_t)g * OUTD + o] = a + bp[o];
    }
  }
}

// ---------------------------------------------------------------------------
extern "C" void kernel_launch(void* const* d_in, const int* in_sizes, int n_in,
                              void* d_out, int out_size, void* d_ws, size_t ws_size,
                              hipStream_t stream) {
  const float* x     = (const float*)d_in[0];
  const int*   sizes = (const int*)d_in[1];
  const float* query = (const float*)d_in[2];
  const float* Wq    = (const float*)d_in[3];
  const float* bq    = (const float*)d_in[4];
  const float* Wk    = (const float*)d_in[5];
  const float* bk    = (const float*)d_in[6];
  const float* Wv    = (const float*)d_in[7];
  const float* bv    = (const float*)d_in[8];
  const float* Wo    = (const float*)d_in[9];
  const float* bo    = (const float*)d_in[10];
  const float* Wp    = (const float*)d_in[11];
  const float* bp    = (const float*)d_in[12];
  float* wsf = (float*)d_ws;
  float* out = (float*)d_out;

  hipLaunchKernelGGL(k0_prep, dim3(1), dim3(384), 0, stream,
                     sizes, query, Wq, bq, Wk, bk, wsf);
  hipLaunchKernelGGL(k1_scores, dim3(1024), dim3(256), 0, stream,
                     x, wsf, wsf + WS_SC);
  hipLaunchKernelGGL(k2_pool, dim3(768), dim3(128), 0, stream,
                     x, sizes, wsf, wsf + WS_XBAR);
  hipLaunchKernelGGL(k3_chain, dim3((G + TG - 1) / TG), dim3(256), 0, stream,
                     wsf + WS_XBAR, Wv, bv, Wo, bo, Wp, bp, out);
}